// Round 3
// baseline (114.752 us; speedup 1.0000x reference)
//
#include <hip/hip_runtime.h>
#include <stdint.h>

#define EPS 1e-5f

typedef short bf16x8 __attribute__((ext_vector_type(8)));
typedef float f32x4 __attribute__((ext_vector_type(4)));

constexpr int M = 1024, N = 4096, K = 4096;
constexpr int BM = 64, BN = 128, BK = 64;
constexpr int NTK = K / BK;           // 64 K-steps

// prep grid
constexpr int PREP_BLOCKS = 2048;
constexpr int64_t W4 = (int64_t)N * K / 4;   // 4,194,304 float4
constexpr int64_t X4 = (int64_t)M * K / 4;   // 1,048,576 float4
// per-block contiguous chunks
constexpr int W4_PER_BLK = (int)(W4 / PREP_BLOCKS);   // 2048 float4 = 1024 pairs
constexpr int X4_PER_BLK = (int)(X4 / PREP_BLOCKS);   // 512 float4  = 256 pairs
static_assert(W4 % PREP_BLOCKS == 0 && X4 % PREP_BLOCKS == 0, "divide");
static_assert(W4_PER_BLK / 2 == 4 * 256, "W: 4 pair-iters per thread");
static_assert(X4_PER_BLK / 2 == 1 * 256, "X: 1 pair-iter per thread");

// ---------- helpers ----------
__device__ __forceinline__ unsigned short f2bf(float f) {
  union { float f; uint32_t u; } v; v.f = f;
  uint32_t r = (v.u + 0x7fffu + ((v.u >> 16) & 1u)) >> 16;  // RNE
  return (unsigned short)r;
}

__device__ __forceinline__ f32x4 ntload(const f32x4* p) {
  return __builtin_nontemporal_load(p);
}

__device__ __forceinline__ void gload16(const void* g, void* l) {
  __builtin_amdgcn_global_load_lds(
      (const __attribute__((address_space(1))) void*)(uintptr_t)g,
      (__attribute__((address_space(3))) void*)(uintptr_t)l, 16, 0, 0);
}

__device__ __forceinline__ void cvt8(const f32x4& a0, const f32x4& a1,
                                     const f32x4& s0, const f32x4& s1,
                                     const f32x4& n0, const f32x4& n1,
                                     bf16x8& o) {
  o[0] = (short)f2bf(a0[0] + n0[0] * fmaxf(__expf(s0[0]), EPS));
  o[1] = (short)f2bf(a0[1] + n0[1] * fmaxf(__expf(s0[1]), EPS));
  o[2] = (short)f2bf(a0[2] + n0[2] * fmaxf(__expf(s0[2]), EPS));
  o[3] = (short)f2bf(a0[3] + n0[3] * fmaxf(__expf(s0[3]), EPS));
  o[4] = (short)f2bf(a1[0] + n1[0] * fmaxf(__expf(s1[0]), EPS));
  o[5] = (short)f2bf(a1[1] + n1[1] * fmaxf(__expf(s1[1]), EPS));
  o[6] = (short)f2bf(a1[2] + n1[2] * fmaxf(__expf(s1[2]), EPS));
  o[7] = (short)f2bf(a1[3] + n1[3] * fmaxf(__expf(s1[3]), EPS));
}

// ---------- prep v3: block-contiguous chunks, NT loads, 16B stores ----------
__global__ __launch_bounds__(256) void prep_kernel(
    const float* __restrict__ wm, const float* __restrict__ wsp,
    const float* __restrict__ nw, const float* __restrict__ bm,
    const float* __restrict__ bsp, const float* __restrict__ nb,
    const float* __restrict__ x,
    unsigned short* __restrict__ w_bf, unsigned short* __restrict__ x_bf,
    float* __restrict__ bias)
{
  const int tid = threadIdx.x;
  const int bid = blockIdx.x;
  const f32x4* wm4  = (const f32x4*)wm;
  const f32x4* wsp4 = (const f32x4*)wsp;
  const f32x4* nw4  = (const f32x4*)nw;
  const f32x4* x4   = (const f32x4*)x;
  bf16x8* wb8 = (bf16x8*)w_bf;
  bf16x8* xb8 = (bf16x8*)x_bf;

  // ---- W region: block owns [bid*2048, bid*2048+2048) float4 (32 KB/array) ----
  {
    const int64_t base4 = (int64_t)bid * W4_PER_BLK;       // float4 units
    const int64_t base8 = base4 >> 1;                      // bf16x8 units
#pragma unroll
    for (int it = 0; it < 4; ++it) {
      const int p = it * 256 + tid;                        // pair index in block
      const int64_t i = base4 + (int64_t)p * 2;
      f32x4 a0 = ntload(wm4  + i), a1 = ntload(wm4  + i + 1);
      f32x4 s0 = ntload(wsp4 + i), s1 = ntload(wsp4 + i + 1);
      f32x4 n0 = ntload(nw4  + i), n1 = ntload(nw4  + i + 1);
      bf16x8 o;
      cvt8(a0, a1, s0, s1, n0, n1, o);
      wb8[base8 + p] = o;
    }
  }

  // ---- X region: block owns [bid*512, bid*512+512) float4 (8 KB) ----
  {
    const int64_t base4 = (int64_t)bid * X4_PER_BLK;
    const int64_t i = base4 + (int64_t)tid * 2;
    f32x4 v0 = ntload(x4 + i), v1 = ntload(x4 + i + 1);
    bf16x8 o;
    o[0] = (short)f2bf(v0[0]); o[1] = (short)f2bf(v0[1]);
    o[2] = (short)f2bf(v0[2]); o[3] = (short)f2bf(v0[3]);
    o[4] = (short)f2bf(v1[0]); o[5] = (short)f2bf(v1[1]);
    o[6] = (short)f2bf(v1[2]); o[7] = (short)f2bf(v1[3]);
    xb8[(base4 >> 1) + tid] = o;
  }

  // ---- bias: first 1024 global threads, one float4 each ----
  const int64_t gt = (int64_t)bid * 256 + tid;
  if (gt < N / 4) {
    float4 a = ((const float4*)bm)[gt];
    float4 s = ((const float4*)bsp)[gt];
    float4 n = ((const float4*)nb)[gt];
    float4 o;
    o.x = a.x + n.x * fmaxf(__expf(s.x), EPS);
    o.y = a.y + n.y * fmaxf(__expf(s.y), EPS);
    o.z = a.z + n.z * fmaxf(__expf(s.z), EPS);
    o.w = a.w + n.w * fmaxf(__expf(s.w), EPS);
    ((float4*)bias)[gt] = o;
  }
}

// ---------- GEMM: out = x_bf @ w_bf^T + bias (unchanged) ----------
__global__ __launch_bounds__(256) void gemm_kernel(
    const unsigned short* __restrict__ Abf,
    const unsigned short* __restrict__ Bbf,
    const float* __restrict__ bias,
    float* __restrict__ out)
{
  __shared__ unsigned short lds_mem[2][(BM + BN) * BK];  // 48 KB

  const int nwg = gridDim.x;
  const int bid = blockIdx.x;
  const int lid = (bid % 8) * (nwg / 8) + bid / 8;
  const int bc = lid >> 4;   // N-tile, 0..31
  const int br = lid & 15;   // M-tile, 0..15

  const int tid = threadIdx.x;
  const int lane = tid & 63;
  const int wid = tid >> 6;

  const int srow = wid * 8 + (lane >> 3);
  const int scol = (lane & 7) * 8;
  const unsigned short* gA = Abf + (int64_t)(br * BM + srow) * K + scol;
  const unsigned short* gB = Bbf + (int64_t)(bc * BN + srow) * K + scol;

  unsigned short* ldsA0 = &lds_mem[0][0];
  unsigned short* ldsB0 = &lds_mem[0][BM * BK];
  unsigned short* ldsA1 = &lds_mem[1][0];
  unsigned short* ldsB1 = &lds_mem[1][BM * BK];
  const int woff = wid * 8 * BK;

  auto stage = [&](int b, int t) {
    const unsigned short* ga = gA + t * BK;
    const unsigned short* gb = gB + t * BK;
    unsigned short* la = (b ? ldsA1 : ldsA0) + woff;
    unsigned short* lb = (b ? ldsB1 : ldsB0) + woff;
    gload16(ga,          la);
    gload16(ga + 32 * K, la + 32 * BK);
    gload16(gb,          lb);
    gload16(gb + 32 * K, lb + 32 * BK);
    gload16(gb + 64 * K, lb + 64 * BK);
    gload16(gb + 96 * K, lb + 96 * BK);
  };

  f32x4 acc[2][4] = {};
  const int fr = lane & 15;
  const int fk = (lane >> 4) << 3;
  const int am = (wid >> 1) * 32;
  const int an = (wid & 1) * 64;

  stage(0, 0);

  int cur = 0;
  for (int t = 0; t < NTK; ++t) {
    __syncthreads();
    if (t + 1 < NTK) stage(cur ^ 1, t + 1);
    const unsigned short* lA = cur ? ldsA1 : ldsA0;
    const unsigned short* lB = cur ? ldsB1 : ldsB0;
#pragma unroll
    for (int kk = 0; kk < 2; ++kk) {
      const int ko = kk * 32 + fk;
      bf16x8 a0 = *(const bf16x8*)&lA[(am +  0 + fr) * BK + ko];
      bf16x8 a1 = *(const bf16x8*)&lA[(am + 16 + fr) * BK + ko];
      bf16x8 b0 = *(const bf16x8*)&lB[(an +  0 + fr) * BK + ko];
      bf16x8 b1 = *(const bf16x8*)&lB[(an + 16 + fr) * BK + ko];
      bf16x8 b2 = *(const bf16x8*)&lB[(an + 32 + fr) * BK + ko];
      bf16x8 b3 = *(const bf16x8*)&lB[(an + 48 + fr) * BK + ko];
      acc[0][0] = __builtin_amdgcn_mfma_f32_16x16x32_bf16(a0, b0, acc[0][0], 0, 0, 0);
      acc[0][1] = __builtin_amdgcn_mfma_f32_16x16x32_bf16(a0, b1, acc[0][1], 0, 0, 0);
      acc[0][2] = __builtin_amdgcn_mfma_f32_16x16x32_bf16(a0, b2, acc[0][2], 0, 0, 0);
      acc[0][3] = __builtin_amdgcn_mfma_f32_16x16x32_bf16(a0, b3, acc[0][3], 0, 0, 0);
      acc[1][0] = __builtin_amdgcn_mfma_f32_16x16x32_bf16(a1, b0, acc[1][0], 0, 0, 0);
      acc[1][1] = __builtin_amdgcn_mfma_f32_16x16x32_bf16(a1, b1, acc[1][1], 0, 0, 0);
      acc[1][2] = __builtin_amdgcn_mfma_f32_16x16x32_bf16(a1, b2, acc[1][2], 0, 0, 0);
      acc[1][3] = __builtin_amdgcn_mfma_f32_16x16x32_bf16(a1, b3, acc[1][3], 0, 0, 0);
    }
    cur ^= 1;
  }

  const int orow0 = br * BM + am + (lane >> 4) * 4;
  const int ocol0 = bc * BN + an + fr;
#pragma unroll
  for (int i = 0; i < 2; ++i) {
#pragma unroll
    for (int j = 0; j < 4; ++j) {
      const int col = ocol0 + j * 16;
      const float bv = bias[col];
      const int row = orow0 + i * 16;
#pragma unroll
      for (int r = 0; r < 4; ++r)
        out[(int64_t)(row + r) * N + col] = acc[i][j][r] + bv;
    }
  }
}

// ---------- correctness fallback if workspace too small ----------
__global__ __launch_bounds__(256) void fallback_kernel(
    const float* __restrict__ x, const float* __restrict__ wm,
    const float* __restrict__ wsp, const float* __restrict__ bm,
    const float* __restrict__ bsp, const float* __restrict__ nw,
    const float* __restrict__ nb, float* __restrict__ out)
{
  int64_t idx = (int64_t)blockIdx.x * 256 + threadIdx.x;
  if (idx >= (int64_t)M * N) return;
  int b = (int)(idx >> 12);
  int o = (int)(idx & (N - 1));
  const float* xr = x + (int64_t)b * K;
  const float* wmr = wm + (int64_t)o * K;
  const float* wsr = wsp + (int64_t)o * K;
  const float* nwr = nw + (int64_t)o * K;
  float s = 0.f;
  for (int k = 0; k < K; ++k)
    s += xr[k] * (wmr[k] + nwr[k] * fmaxf(__expf(wsr[k]), EPS));
  out[idx] = s + bm[o] + nb[o] * fmaxf(__expf(bsp[o]), EPS);
}

extern "C" void kernel_launch(void* const* d_in, const int* in_sizes, int n_in,
                              void* d_out, int out_size, void* d_ws, size_t ws_size,
                              hipStream_t stream) {
  const float* x   = (const float*)d_in[0];
  const float* wm  = (const float*)d_in[1];
  const float* wsp = (const float*)d_in[2];
  const float* bm  = (const float*)d_in[3];
  const float* bsp = (const float*)d_in[4];
  const float* nw  = (const float*)d_in[5];
  const float* nb  = (const float*)d_in[6];
  float* out = (float*)d_out;

  const size_t w_bytes = (size_t)N * K * 2;
  const size_t x_bytes = (size_t)M * K * 2;
  const size_t b_bytes = (size_t)N * 4;
  if (ws_size < w_bytes + x_bytes + b_bytes) {
    fallback_kernel<<<(int)(((int64_t)M * N + 255) / 256), 256, 0, stream>>>(
        x, wm, wsp, bm, bsp, nw, nb, out);
    return;
  }

  char* ws = (char*)d_ws;
  unsigned short* w_bf = (unsigned short*)ws;
  unsigned short* x_bf = (unsigned short*)(ws + w_bytes);
  float* bias = (float*)(ws + w_bytes + x_bytes);

  prep_kernel<<<PREP_BLOCKS, 256, 0, stream>>>(wm, wsp, nw, bm, bsp, nb, x, w_bf, x_bf, bias);
  gemm_kernel<<<(M / BM) * (N / BN), 256, 0, stream>>>(x_bf, w_bf, bias, out);
}

// Round 4
// 84.033 us; speedup vs baseline: 1.3655x; 1.3655x over previous
//
#include <hip/hip_runtime.h>
#include <stdint.h>

#define EPS 1e-5f

typedef short bf16x8 __attribute__((ext_vector_type(8)));
typedef float f32x4 __attribute__((ext_vector_type(4)));

constexpr int M = 1024, N = 4096, K = 4096;
constexpr int BM = 64, BN = 128, BK = 64;
constexpr int NTK = K / BK;           // 64 K-steps

// prep grid
constexpr int PREP_BLOCKS = 2048;
constexpr int64_t W4 = (int64_t)N * K / 4;   // 4,194,304 float4
constexpr int64_t X4 = (int64_t)M * K / 4;   // 1,048,576 float4
constexpr int W4_PER_BLK = (int)(W4 / PREP_BLOCKS);   // 2048 float4
constexpr int X4_PER_BLK = (int)(X4 / PREP_BLOCKS);   // 512 float4
static_assert(W4 % PREP_BLOCKS == 0 && X4 % PREP_BLOCKS == 0, "divide");

// ---------- helpers ----------
__device__ __forceinline__ unsigned short f2bf(float f) {
  union { float f; uint32_t u; } v; v.f = f;
  uint32_t r = (v.u + 0x7fffu + ((v.u >> 16) & 1u)) >> 16;  // RNE
  return (unsigned short)r;
}

__device__ __forceinline__ void gload16(const void* g, void* l) {
  __builtin_amdgcn_global_load_lds(
      (const __attribute__((address_space(1))) void*)(uintptr_t)g,
      (__attribute__((address_space(3))) void*)(uintptr_t)l, 16, 0, 0);
}

__device__ __forceinline__ void cvt8(const f32x4& a0, const f32x4& a1,
                                     const f32x4& s0, const f32x4& s1,
                                     const f32x4& n0, const f32x4& n1,
                                     bf16x8& o) {
  o[0] = (short)f2bf(a0[0] + n0[0] * fmaxf(__expf(s0[0]), EPS));
  o[1] = (short)f2bf(a0[1] + n0[1] * fmaxf(__expf(s0[1]), EPS));
  o[2] = (short)f2bf(a0[2] + n0[2] * fmaxf(__expf(s0[2]), EPS));
  o[3] = (short)f2bf(a0[3] + n0[3] * fmaxf(__expf(s0[3]), EPS));
  o[4] = (short)f2bf(a1[0] + n1[0] * fmaxf(__expf(s1[0]), EPS));
  o[5] = (short)f2bf(a1[1] + n1[1] * fmaxf(__expf(s1[1]), EPS));
  o[6] = (short)f2bf(a1[2] + n1[2] * fmaxf(__expf(s1[2]), EPS));
  o[7] = (short)f2bf(a1[3] + n1[3] * fmaxf(__expf(s1[3]), EPS));
}

// ---------- prep v4: block-contiguous chunks, NORMAL loads (L3 reuse), 16B stores ----------
__global__ __launch_bounds__(256) void prep_kernel(
    const float* __restrict__ wm, const float* __restrict__ wsp,
    const float* __restrict__ nw, const float* __restrict__ bm,
    const float* __restrict__ bsp, const float* __restrict__ nb,
    const float* __restrict__ x,
    unsigned short* __restrict__ w_bf, unsigned short* __restrict__ x_bf,
    float* __restrict__ bias)
{
  const int tid = threadIdx.x;
  const int bid = blockIdx.x;
  const f32x4* wm4  = (const f32x4*)wm;
  const f32x4* wsp4 = (const f32x4*)wsp;
  const f32x4* nw4  = (const f32x4*)nw;
  const f32x4* x4   = (const f32x4*)x;
  bf16x8* wb8 = (bf16x8*)w_bf;
  bf16x8* xb8 = (bf16x8*)x_bf;

  // ---- W region: block owns a contiguous 32 KB window of each array ----
  {
    const int64_t base4 = (int64_t)bid * W4_PER_BLK;
    const int64_t base8 = base4 >> 1;
#pragma unroll
    for (int it = 0; it < 4; ++it) {
      const int p = it * 256 + tid;
      const int64_t i = base4 + (int64_t)p * 2;
      f32x4 a0 = wm4[i],  a1 = wm4[i + 1];
      f32x4 s0 = wsp4[i], s1 = wsp4[i + 1];
      f32x4 n0 = nw4[i],  n1 = nw4[i + 1];
      bf16x8 o;
      cvt8(a0, a1, s0, s1, n0, n1, o);
      wb8[base8 + p] = o;
    }
  }

  // ---- X region ----
  {
    const int64_t base4 = (int64_t)bid * X4_PER_BLK;
    const int64_t i = base4 + (int64_t)tid * 2;
    f32x4 v0 = x4[i], v1 = x4[i + 1];
    bf16x8 o;
    o[0] = (short)f2bf(v0[0]); o[1] = (short)f2bf(v0[1]);
    o[2] = (short)f2bf(v0[2]); o[3] = (short)f2bf(v0[3]);
    o[4] = (short)f2bf(v1[0]); o[5] = (short)f2bf(v1[1]);
    o[6] = (short)f2bf(v1[2]); o[7] = (short)f2bf(v1[3]);
    xb8[(base4 >> 1) + tid] = o;
  }

  // ---- bias ----
  const int64_t gt = (int64_t)bid * 256 + tid;
  if (gt < N / 4) {
    float4 a = ((const float4*)bm)[gt];
    float4 s = ((const float4*)bsp)[gt];
    float4 n = ((const float4*)nb)[gt];
    float4 o;
    o.x = a.x + n.x * fmaxf(__expf(s.x), EPS);
    o.y = a.y + n.y * fmaxf(__expf(s.y), EPS);
    o.z = a.z + n.z * fmaxf(__expf(s.z), EPS);
    o.w = a.w + n.w * fmaxf(__expf(s.w), EPS);
    ((float4*)bias)[gt] = o;
  }
}

// ---------- GEMM with XOR-swizzled LDS (T2 via pre-swizzled global source) ----------
// LDS layout: LDS(row, slot s) holds global (row, slot s ^ (row&7)), slots = 16B units.
// Staging: linear global_load_lds dest; lane loads global slot (lane&7)^(lane>>3).
// Reads: col_elem = ((slot ^ (row&7)) << 3); all of a thread's fragment rows share
// row&7 == lane&7, so the swizzled col is a per-thread constant per kk.
__global__ __launch_bounds__(256) void gemm_kernel(
    const unsigned short* __restrict__ Abf,
    const unsigned short* __restrict__ Bbf,
    const float* __restrict__ bias,
    float* __restrict__ out)
{
  __shared__ unsigned short lds_mem[2][(BM + BN) * BK];  // 48 KB

  const int nwg = gridDim.x;
  const int bid = blockIdx.x;
  const int lid = (bid % 8) * (nwg / 8) + bid / 8;
  const int bc = lid >> 4;   // N-tile, 0..31
  const int br = lid & 15;   // M-tile, 0..15

  const int tid = threadIdx.x;
  const int lane = tid & 63;
  const int wid = tid >> 6;

  // staging: pre-swizzled source slot
  const int srow = wid * 8 + (lane >> 3);
  const int scol = (((lane & 7) ^ (lane >> 3)) * 8);   // XOR-swizzled 16B slot
  const unsigned short* gA = Abf + (int64_t)(br * BM + srow) * K + scol;
  const unsigned short* gB = Bbf + (int64_t)(bc * BN + srow) * K + scol;

  unsigned short* ldsA0 = &lds_mem[0][0];
  unsigned short* ldsB0 = &lds_mem[0][BM * BK];
  unsigned short* ldsA1 = &lds_mem[1][0];
  unsigned short* ldsB1 = &lds_mem[1][BM * BK];
  const int woff = wid * 8 * BK;

  auto stage = [&](int b, int t) {
    const unsigned short* ga = gA + t * BK;
    const unsigned short* gb = gB + t * BK;
    unsigned short* la = (b ? ldsA1 : ldsA0) + woff;
    unsigned short* lb = (b ? ldsB1 : ldsB0) + woff;
    gload16(ga,          la);
    gload16(ga + 32 * K, la + 32 * BK);
    gload16(gb,          lb);
    gload16(gb + 32 * K, lb + 32 * BK);
    gload16(gb + 64 * K, lb + 64 * BK);
    gload16(gb + 96 * K, lb + 96 * BK);
  };

  f32x4 acc[2][4] = {};
  const int fr = lane & 15;
  const int hi = lane >> 4;            // 0..3 -> k-slot within 32-K half
  const int rl = lane & 7;             // row&7 of every fragment row this thread reads
  // swizzled column (element units) for kk=0 (slot=hi) and kk=1 (slot=4+hi)
  const int c0 = ((hi ^ rl) << 3);
  const int c1 = (((4 + hi) ^ rl) << 3);
  const int am = (wid >> 1) * 32;
  const int an = (wid & 1) * 64;

  stage(0, 0);

  int cur = 0;
  for (int t = 0; t < NTK; ++t) {
    __syncthreads();
    if (t + 1 < NTK) stage(cur ^ 1, t + 1);
    const unsigned short* lA = cur ? ldsA1 : ldsA0;
    const unsigned short* lB = cur ? ldsB1 : ldsB0;
#pragma unroll
    for (int kk = 0; kk < 2; ++kk) {
      const int c = kk ? c1 : c0;
      bf16x8 a0 = *(const bf16x8*)&lA[(am +  0 + fr) * BK + c];
      bf16x8 a1 = *(const bf16x8*)&lA[(am + 16 + fr) * BK + c];
      bf16x8 b0 = *(const bf16x8*)&lB[(an +  0 + fr) * BK + c];
      bf16x8 b1 = *(const bf16x8*)&lB[(an + 16 + fr) * BK + c];
      bf16x8 b2 = *(const bf16x8*)&lB[(an + 32 + fr) * BK + c];
      bf16x8 b3 = *(const bf16x8*)&lB[(an + 48 + fr) * BK + c];
      acc[0][0] = __builtin_amdgcn_mfma_f32_16x16x32_bf16(a0, b0, acc[0][0], 0, 0, 0);
      acc[0][1] = __builtin_amdgcn_mfma_f32_16x16x32_bf16(a0, b1, acc[0][1], 0, 0, 0);
      acc[0][2] = __builtin_amdgcn_mfma_f32_16x16x32_bf16(a0, b2, acc[0][2], 0, 0, 0);
      acc[0][3] = __builtin_amdgcn_mfma_f32_16x16x32_bf16(a0, b3, acc[0][3], 0, 0, 0);
      acc[1][0] = __builtin_amdgcn_mfma_f32_16x16x32_bf16(a1, b0, acc[1][0], 0, 0, 0);
      acc[1][1] = __builtin_amdgcn_mfma_f32_16x16x32_bf16(a1, b1, acc[1][1], 0, 0, 0);
      acc[1][2] = __builtin_amdgcn_mfma_f32_16x16x32_bf16(a1, b2, acc[1][2], 0, 0, 0);
      acc[1][3] = __builtin_amdgcn_mfma_f32_16x16x32_bf16(a1, b3, acc[1][3], 0, 0, 0);
    }
    cur ^= 1;
  }

  const int orow0 = br * BM + am + (lane >> 4) * 4;
  const int ocol0 = bc * BN + an + fr;
#pragma unroll
  for (int i = 0; i < 2; ++i) {
#pragma unroll
    for (int j = 0; j < 4; ++j) {
      const int col = ocol0 + j * 16;
      const float bv = bias[col];
      const int row = orow0 + i * 16;
#pragma unroll
      for (int r = 0; r < 4; ++r)
        out[(int64_t)(row + r) * N + col] = acc[i][j][r] + bv;
    }
  }
}

// ---------- correctness fallback if workspace too small ----------
__global__ __launch_bounds__(256) void fallback_kernel(
    const float* __restrict__ x, const float* __restrict__ wm,
    const float* __restrict__ wsp, const float* __restrict__ bm,
    const float* __restrict__ bsp, const float* __restrict__ nw,
    const float* __restrict__ nb, float* __restrict__ out)
{
  int64_t idx = (int64_t)blockIdx.x * 256 + threadIdx.x;
  if (idx >= (int64_t)M * N) return;
  int b = (int)(idx >> 12);
  int o = (int)(idx & (N - 1));
  const float* xr = x + (int64_t)b * K;
  const float* wmr = wm + (int64_t)o * K;
  const float* wsr = wsp + (int64_t)o * K;
  const float* nwr = nw + (int64_t)o * K;
  float s = 0.f;
  for (int k = 0; k < K; ++k)
    s += xr[k] * (wmr[k] + nwr[k] * fmaxf(__expf(wsr[k]), EPS));
  out[idx] = s + bm[o] + nb[o] * fmaxf(__expf(bsp[o]), EPS);
}

extern "C" void kernel_launch(void* const* d_in, const int* in_sizes, int n_in,
                              void* d_out, int out_size, void* d_ws, size_t ws_size,
                              hipStream_t stream) {
  const float* x   = (const float*)d_in[0];
  const float* wm  = (const float*)d_in[1];
  const float* wsp = (const float*)d_in[2];
  const float* bm  = (const float*)d_in[3];
  const float* bsp = (const float*)d_in[4];
  const float* nw  = (const float*)d_in[5];
  const float* nb  = (const float*)d_in[6];
  float* out = (float*)d_out;

  const size_t w_bytes = (size_t)N * K * 2;
  const size_t x_bytes = (size_t)M * K * 2;
  const size_t b_bytes = (size_t)N * 4;
  if (ws_size < w_bytes + x_bytes + b_bytes) {
    fallback_kernel<<<(int)(((int64_t)M * N + 255) / 256), 256, 0, stream>>>(
        x, wm, wsp, bm, bsp, nw, nb, out);
    return;
  }

  char* ws = (char*)d_ws;
  unsigned short* w_bf = (unsigned short*)ws;
  unsigned short* x_bf = (unsigned short*)(ws + w_bytes);
  float* bias = (float*)(ws + w_bytes + x_bytes);

  prep_kernel<<<PREP_BLOCKS, 256, 0, stream>>>(wm, wsp, nw, bm, bsp, nb, x, w_bf, x_bf, bias);
  gemm_kernel<<<(M / BM) * (N / BN), 256, 0, stream>>>(x_bf, w_bf, bias, out);
}